// Round 2
// baseline (54305.768 us; speedup 1.0000x reference)
//
#include <hip/hip_runtime.h>
#include <stdint.h>

// DiffusionModel R6: packed fp32 noise pipeline via IR-level vector ops.
// R5 post-mortem: hand-written v_pk_*_f32 inline asm produced structurally
// wrong packed halves (suspect VOP3P op_sel_hi defaults in the asm parser) ->
// absmax 0.76. R6 expresses the same packing as ext_vector_type(2) arithmetic
// (+ __builtin_elementwise_fma): per-element IEEE guaranteed at IR level, and
// the gfx950 backend lowers v2f32 fadd/fmul/fma to v_pk_{add,mul,fma}_f32
// with correct modifiers. Threefry int side (irreducible 3 VALU/round)
// unchanged from the passing R4.
// Numerics vs R4 (which passed at absmax 3.9e-3, threshold 2e-2):
//  - vector ops are per-half bit-identical to R4's scalar ops
//  - w = -__logf(u): __logf kept verbatim per element; s = w - 2.5 computed as
//    fma(L, -1, -2.5) == RN(-L - 2.5) == (neg; sub) exactly
//  - rare erfinv tail (P~0.34%/draw): packed common poly for all, rare halves
//    overwritten per-lane with the exact R4 rare polynomial

#define NTOTAL 25165824u
#define EPT    4u
#define NTHREADS (NTOTAL / EPT)   // 6,291,456 threads = 24576 blocks x 256
#define TS     1000

typedef float f32x2 __attribute__((ext_vector_type(2)));

__device__ __forceinline__ uint32_t rotl32(uint32_t x, int r) {
  // alignbit(a,b,c) = (a:b) >> c  =>  alignbit(x,x,32-r) = rotl(x,r)
  return __builtin_amdgcn_alignbit(x, x, 32 - r);
}

__device__ __forceinline__ void tf2x32(uint32_t k0, uint32_t k1,
                                       uint32_t x0, uint32_t x1,
                                       uint32_t& o0, uint32_t& o1) {
  const uint32_t k2 = k0 ^ k1 ^ 0x1BD11BDAu;
  x0 += k0; x1 += k1;
#define RR(r) { x0 += x1; x1 = rotl32(x1, r); x1 ^= x0; }
  RR(13) RR(15) RR(26) RR(6)
  x0 += k1; x1 += k2 + 1u;
  RR(17) RR(29) RR(16) RR(24)
  x0 += k2; x1 += k0 + 2u;
  RR(13) RR(15) RR(26) RR(6)
  x0 += k0; x1 += k1 + 3u;
  RR(17) RR(29) RR(16) RR(24)
  x0 += k1; x1 += k2 + 4u;
  RR(13) RR(15) RR(26) RR(6)
  x0 += k2; x1 += k0 + 5u;
#undef RR
  o0 = x0; o1 = x1;
}

// partitionable random_bits(32): counter (0, i), XOR-fold the two outputs.
__device__ __forceinline__ uint32_t tf_bits(uint32_t k0, uint32_t k1, uint32_t i) {
  uint32_t o0, o1;
  tf2x32(k0, k1, 0u, i, o0, o1);
  return o0 ^ o1;
}

// packed fma: llvm.fma.v2f32 -> v_pk_fma_f32 (gfx90a+ packed-FP32), exact
// per-element IEEE fma, same rounding as scalar fmaf.
__device__ __forceinline__ f32x2 pk_fma(f32x2 a, f32x2 b, f32x2 c) {
  return __builtin_elementwise_fma(a, b, c);
}

__device__ __forceinline__ float clamp01(float v) {
  return __builtin_amdgcn_fmed3f(v, 0.0f, 1.0f);  // == min(1,max(0,v)) finite
}

// Rare erfinv tail (w >= 5), exact R4 sequence. Executed under divergent
// per-lane mask ~0.34% of draws; literals fine here (cold).
__device__ __forceinline__ float rare_poly(float w) {
#pragma clang fp contract(off)
  float s = sqrtf(w) - 3.0f;
  float p = -0.000200214257f;
  p = fmaf(p, s, 0.000100950558f);
  p = fmaf(p, s, 0.00134934322f);
  p = fmaf(p, s, -0.00367342844f);
  p = fmaf(p, s, 0.00573950773f);
  p = fmaf(p, s, -0.0076224613f);
  p = fmaf(p, s, 0.00943887047f);
  p = fmaf(p, s, 1.00167406f);
  p = fmaf(p, s, 2.83297682f);
  return p;
}

// noise = 0.1*sqrt2 * erfinv(bits_to_u(b)) for a PAIR of elements.
// Per-half identical to R4's scalar noise_from_bits.
__device__ __forceinline__ f32x2 noise2(uint32_t b0, uint32_t b1) {
#pragma clang fp contract(off)
  f32x2 fv;
  fv.x = __uint_as_float((b0 >> 9) | 0x3f800000u);
  fv.y = __uint_as_float((b1 >> 9) | 0x3f800000u);
  const f32x2 kTwo = {2.0f, 2.0f};
  const f32x2 kLo  = {-0.99999994f, -0.99999994f};
  f32x2 fm = fv - 1.0f;            // per-half == scalar (f - 1.0f)
  f32x2 xx = pk_fma(fm, kTwo, kLo);// u in (-1,1); fmax(lo,.) provably no-op
  f32x2 t  = xx * xx;
  f32x2 u  = 1.0f - t;             // two roundings, ref-identical; NOT fma
  float L0 = __logf(u.x);          // exact R4: w = -__logf(u); u normal
  float L1 = __logf(u.y);
  f32x2 wn = {L0, L1};             // wn == -w
  const f32x2 kM1  = {-1.0f, -1.0f};
  const f32x2 kM25 = {-2.5f, -2.5f};
  f32x2 s = pk_fma(wn, kM1, kM25); // RN(-L - 2.5) == (w - 2.5) exactly
  f32x2 p = {2.81022636e-08f, 2.81022636e-08f};
  const f32x2 kC1 = {3.43273939e-07f, 3.43273939e-07f};
  const f32x2 kC2 = {-3.5233877e-06f, -3.5233877e-06f};
  const f32x2 kC3 = {-4.39150654e-06f, -4.39150654e-06f};
  const f32x2 kC4 = {0.00021858087f, 0.00021858087f};
  const f32x2 kC5 = {-0.00125372503f, -0.00125372503f};
  const f32x2 kC6 = {-0.00417768164f, -0.00417768164f};
  const f32x2 kC7 = {0.246640727f, 0.246640727f};
  const f32x2 kC8 = {1.50140941f, 1.50140941f};
  p = pk_fma(p, s, kC1);
  p = pk_fma(p, s, kC2);
  p = pk_fma(p, s, kC3);
  p = pk_fma(p, s, kC4);
  p = pk_fma(p, s, kC5);
  p = pk_fma(p, s, kC6);
  p = pk_fma(p, s, kC7);
  p = pk_fma(p, s, kC8);
  // rare tail fixup: w >= 5  <=>  L <= -5. Overwrite halves with exact R4 path.
  if (__builtin_expect(!(fminf(L0, L1) > -5.0f), 0)) {
    if (!(L0 > -5.0f)) p.x = rare_poly(-L0);
    if (!(L1 > -5.0f)) p.y = rare_poly(-L1);
  }
  f32x2 px = p * xx;                    // erfinv = p * x  (same order as R4)
  const float c = 0.1f * 1.41421356f;   // host-folded, single rounding
  return c * px;                        // c * erfinv     (same order as R4)
}

__global__ __launch_bounds__(256) void diffusion_kernel(
    const float* __restrict__ x, float* __restrict__ out) {
#pragma clang fp contract(off)
  // Step keys (partitionable split): key_t = threefry((0,1), (0,t)).
  // +1 pad slot so the t+1 prefetch never reads OOB.
  __shared__ alignas(16) uint2 skeys[TS + 1];
  const int tid = threadIdx.x;
  for (int j = tid; j < TS + 1; j += 256) {
    uint32_t o0, o1;
    tf2x32(0u, 1u, 0u, (uint32_t)(j < TS ? j : 0), o0, o1);
    skeys[j] = make_uint2(o0, o1);
  }
  __syncthreads();

  const uint32_t i = blockIdx.x * 256u + (uint32_t)tid;  // exact grid
  const uint32_t base = i * EPT;

  float4 xv = ((const float4*)x)[i];
  f32x2 v01 = {xv.x, xv.y};
  f32x2 v23 = {xv.z, xv.w};

  uint2 kcur = skeys[0];
  for (int t = 0; t < TS; ++t) {
    const uint32_t k0 = (uint32_t)__builtin_amdgcn_readfirstlane((int)kcur.x);
    const uint32_t k1 = (uint32_t)__builtin_amdgcn_readfirstlane((int)kcur.y);
    kcur = skeys[t + 1];  // prefetch next key; waitcnt lands far from use
    uint32_t b[EPT];
#pragma unroll
    for (uint32_t e = 0; e < EPT; ++e) b[e] = tf_bits(k0, k1, base + e);
    f32x2 n01 = noise2(b[0], b[1]);
    f32x2 n23 = noise2(b[2], b[3]);
    v01 = v01 + n01;
    v23 = v23 + n23;
    v01.x = clamp01(v01.x); v01.y = clamp01(v01.y);  // med3 has no pk form
    v23.x = clamp01(v23.x); v23.y = clamp01(v23.y);
  }

  // rev_key = fold_in(key(2), 999) = threefry((0,2),(0,999)) — constant-folded.
  uint32_t rk0, rk1;
  tf2x32(0u, 2u, 0u, 999u, rk0, rk1);
  uint32_t rb[EPT];
#pragma unroll
  for (uint32_t e = 0; e < EPT; ++e) rb[e] = tf_bits(rk0, rk1, base + e);
  f32x2 r01 = noise2(rb[0], rb[1]);
  f32x2 r23 = noise2(rb[2], rb[3]);
  float4 ov;
  ov.x = clamp01(v01.x - r01.x);
  ov.y = clamp01(v01.y - r01.y);
  ov.z = clamp01(v23.x - r23.x);
  ov.w = clamp01(v23.y - r23.y);
  ((float4*)out)[i] = ov;
}

extern "C" void kernel_launch(void* const* d_in, const int* in_sizes, int n_in,
                              void* d_out, int out_size, void* d_ws, size_t ws_size,
                              hipStream_t stream) {
  (void)in_sizes; (void)n_in; (void)d_ws; (void)ws_size; (void)out_size;
  const float* x = (const float*)d_in[0];
  float* out = (float*)d_out;
  dim3 block(256);
  dim3 grid(NTHREADS / 256);  // 24576 blocks
  hipLaunchKernelGGL(diffusion_kernel, grid, block, 0, stream, x, out);
}

// Round 3
// 47920.081 us; speedup vs baseline: 1.1333x; 1.1333x over previous
//
#include <hip/hip_runtime.h>
#include <stdint.h>

// DiffusionModel R7: back to the proven R4 scalar skeleton (R6's packing cut
// issue-cycles 7% but regressed 4% from marshalling/ILP stalls — reverted).
// Pure op-count reduction with bounded numeric deviation:
//  1. bits->u via v_cvt_f32_u32: fma((float)(b>>9), 2^-22, lo) is BIT-IDENTICAL
//     to the (b>>9)|0x3f800000 trick (m<2^24 exact in cvt; one rounding both
//     ways). 4 -> 3 ops/elem.
//  2. s = fma(log2(u), -ln2, -2.5) replaces (mul, sub): <=1 ulp shift on s,
//     same deviation class as the accepted log1p->log swap. 3 -> 2 ops/elem.
//  3. Central erfinv poly 9 -> 6 coeffs: dropped-term error <=1.03e-3 only at
//     u~0 where noise ~ 0.1414*|u|*dp -> per-draw <=1e-4, zero bias (odd in
//     u), random-walk over 1000 clipped steps < 1e-3. Saves 3 fma/elem.
//  4. c = 0.1*sqrt2 folded into poly coefficients (compile-time float
//     folding); noise = x * p~. Saves 1 mul/elem, ~1e-7 deviation.
//  5. Tail poly 9 -> 6 coeffs (exec-masked, ~19% of wave-draws): dp <= 2.3e-4
//     at the common w~5 end, ~3.4 tail hits/pixel -> <1e-4 accumulated.
// Threefry int side (72 ops/elem) untouched: exact JAX bits are required.

#define NTOTAL 25165824u
#define EPT    4u
#define NTHREADS (NTOTAL / EPT)   // 6,291,456 threads = 24576 blocks x 256
#define TS     1000

// c = 0.1*sqrt2, host-folded in float exactly as R4 did.
#define KC (0.1f * 1.41421356f)

__device__ __forceinline__ uint32_t rotl32(uint32_t x, int r) {
  // alignbit(a,b,c) = (a:b) >> c  =>  alignbit(x,x,32-r) = rotl(x,r)
  return __builtin_amdgcn_alignbit(x, x, 32 - r);
}

__device__ __forceinline__ void tf2x32(uint32_t k0, uint32_t k1,
                                       uint32_t x0, uint32_t x1,
                                       uint32_t& o0, uint32_t& o1) {
  const uint32_t k2 = k0 ^ k1 ^ 0x1BD11BDAu;
  x0 += k0; x1 += k1;
#define RR(r) { x0 += x1; x1 = rotl32(x1, r); x1 ^= x0; }
  RR(13) RR(15) RR(26) RR(6)
  x0 += k1; x1 += k2 + 1u;
  RR(17) RR(29) RR(16) RR(24)
  x0 += k2; x1 += k0 + 2u;
  RR(13) RR(15) RR(26) RR(6)
  x0 += k0; x1 += k1 + 3u;
  RR(17) RR(29) RR(16) RR(24)
  x0 += k1; x1 += k2 + 4u;
  RR(13) RR(15) RR(26) RR(6)
  x0 += k2; x1 += k0 + 5u;
#undef RR
  o0 = x0; o1 = x1;
}

// partitionable random_bits(32): counter (0, i), XOR-fold the two outputs.
__device__ __forceinline__ uint32_t tf_bits(uint32_t k0, uint32_t k1, uint32_t i) {
  uint32_t o0, o1;
  tf2x32(k0, k1, 0u, i, o0, o1);
  return o0 ^ o1;
}

__device__ __forceinline__ float clamp01(float v) {
  return __builtin_amdgcn_fmed3f(v, 0.0f, 1.0f);  // == min(1,max(0,v)) finite
}

// noise = 0.1*sqrt2 * erfinv(u(b)), c folded into the polynomial coefficients.
__device__ __forceinline__ float noise_from_bits(uint32_t b) {
#pragma clang fp contract(off)
  // u in (-1,1): RN((b>>9)*2^-22 - 0.99999994) — bit-identical to the
  // R4 bit-trick (exact cvt, single fma rounding; fmax(lo,.) provably no-op).
  float mf = (float)(b >> 9);              // v_cvt_f32_u32, exact (< 2^24)
  float x  = fmaf(mf, 0x1p-22f, -0.99999994f);
  float t = x * x;
  float u = 1.0f - t;      // two roundings, ref-identical; do NOT fma
  float L = __log2f(u);    // raw v_log_f32; u >= 1.19e-7, normal
  // s = w - 2.5 where w = -ln(u): fused, <=1 ulp vs (mul, neg-sub)
  float s = fmaf(L, -0x1.62e43p-1f, -2.5f);
  float p;
  if (__builtin_expect(!(s < 2.5f), 0)) {  // w >= 5, P ~ 0.34%/draw
    float s3 = sqrtf(s + 2.5f) - 3.0f;     // sqrt(w) - 3 (+-2ulp arg, benign)
    p = KC * -0.00367342844f;
    p = fmaf(p, s3, KC * 0.00573950773f);
    p = fmaf(p, s3, KC * -0.0076224613f);
    p = fmaf(p, s3, KC * 0.00943887047f);
    p = fmaf(p, s3, KC * 1.00167406f);
    p = fmaf(p, s3, KC * 2.83297682f);
  } else {
    p = KC * -4.39150654e-06f;
    p = fmaf(p, s, KC * 0.00021858087f);
    p = fmaf(p, s, KC * -0.00125372503f);
    p = fmaf(p, s, KC * -0.00417768164f);
    p = fmaf(p, s, KC * 0.246640727f);
    p = fmaf(p, s, KC * 1.50140941f);
  }
  return x * p;  // noise = x * (c*poly)
}

__global__ __launch_bounds__(256) void diffusion_kernel(
    const float* __restrict__ x, float* __restrict__ out) {
  // Step keys (partitionable split): key_t = threefry((0,1), (0,t)).
  // +1 pad slot so the t+1 prefetch never reads OOB.
  __shared__ alignas(16) uint2 skeys[TS + 1];
  const int tid = threadIdx.x;
  for (int j = tid; j < TS + 1; j += 256) {
    uint32_t o0, o1;
    tf2x32(0u, 1u, 0u, (uint32_t)(j < TS ? j : 0), o0, o1);
    skeys[j] = make_uint2(o0, o1);
  }
  __syncthreads();

  const uint32_t i = blockIdx.x * 256u + (uint32_t)tid;  // exact grid
  const uint32_t base = i * EPT;

  float4 xv = ((const float4*)x)[i];
  float v[EPT] = {xv.x, xv.y, xv.z, xv.w};

  uint2 kcur = skeys[0];
  for (int t = 0; t < TS; ++t) {
    const uint32_t k0 = (uint32_t)__builtin_amdgcn_readfirstlane((int)kcur.x);
    const uint32_t k1 = (uint32_t)__builtin_amdgcn_readfirstlane((int)kcur.y);
    kcur = skeys[t + 1];  // prefetch next key; waitcnt lands far from use
    uint32_t b[EPT];
#pragma unroll
    for (uint32_t e = 0; e < EPT; ++e) b[e] = tf_bits(k0, k1, base + e);
#pragma unroll
    for (uint32_t e = 0; e < EPT; ++e) {
      v[e] = clamp01(v[e] + noise_from_bits(b[e]));
    }
  }

  // rev_key = fold_in(key(2), 999) = threefry((0,2),(0,999)) — constant-folded.
  uint32_t rk0, rk1;
  tf2x32(0u, 2u, 0u, 999u, rk0, rk1);
  float4 ov;
  float* op = &ov.x;
#pragma unroll
  for (uint32_t e = 0; e < EPT; ++e) {
    float r = noise_from_bits(tf_bits(rk0, rk1, base + e));
    op[e] = clamp01(v[e] - r);
  }
  ((float4*)out)[i] = ov;
}

extern "C" void kernel_launch(void* const* d_in, const int* in_sizes, int n_in,
                              void* d_out, int out_size, void* d_ws, size_t ws_size,
                              hipStream_t stream) {
  (void)in_sizes; (void)n_in; (void)d_ws; (void)ws_size; (void)out_size;
  const float* x = (const float*)d_in[0];
  float* out = (float*)d_out;
  dim3 block(256);
  dim3 grid(NTHREADS / 256);  // 24576 blocks
  hipLaunchKernelGGL(diffusion_kernel, grid, block, 0, stream, x, out);
}

// Round 4
// 46419.238 us; speedup vs baseline: 1.1699x; 1.0323x over previous
//
#include <hip/hip_runtime.h>
#include <stdint.h>

// DiffusionModel R8 = R7 + two op-count cuts on the proven scalar skeleton:
//  1. Tail boundary w>=5 -> w>=6.5 (s<4.0). Two-sided P(tail/draw) 0.674% ->
//     0.075%, so wave-level tail entry drops 35% -> 4.7% of element-branches
//     (~36 cycles/iter saved). Central 6-coeff poly extrapolated over
//     w in [5,6.5]: |dp| <= 0.008 at s=4 -> |dnoise| <= 1.1e-3 per draw,
//     P=0.6%/draw (~6 draws/pixel) -> accumulated < ~4e-3 worst pixel.
//     Tail poly untouched (Giles fit domain w in [5,16] contains [6.5,14.8];
//     max representable w is 14.8, so no upper escape).
//  2. Threefry injection fusion: inject x1 first, then x0 = x0 + kA + x1
//     (v_add3_u32 pattern, one SGPR operand - legal), and init round as
//     x0 = i + (k0+k1) with k0+k1 on the free SALU pipe. Mod-2^32 associative
//     => bit-exact. ~74 -> ~68 VALU/elem if backend wasn't already fusing.
// R7 analysis recap: VALU-issue-bound (HBM 0.04%, LDS 0, MFMA 0); duration
// tracks VALU op count ~1:1 at ~60% issue efficiency. Keys stay in
// LDS+readfirstlane (s_load scheme audited: ~0.4% upside, SGPR-schedule risk).

#define NTOTAL 25165824u
#define EPT    4u
#define NTHREADS (NTOTAL / EPT)   // 6,291,456 threads = 24576 blocks x 256
#define TS     1000

// c = 0.1*sqrt2, host-folded in float exactly as R4 did.
#define KC (0.1f * 1.41421356f)

__device__ __forceinline__ uint32_t rotl32(uint32_t x, int r) {
  // alignbit(a,b,c) = (a:b) >> c  =>  alignbit(x,x,32-r) = rotl(x,r)
  return __builtin_amdgcn_alignbit(x, x, 32 - r);
}

// Full 20-round threefry2x32 for key derivation (used in preludes only).
__device__ __forceinline__ void tf2x32(uint32_t k0, uint32_t k1,
                                       uint32_t x0, uint32_t x1,
                                       uint32_t& o0, uint32_t& o1) {
  const uint32_t k2 = k0 ^ k1 ^ 0x1BD11BDAu;
  x0 += k0; x1 += k1;
#define RR(r) { x0 += x1; x1 = rotl32(x1, r); x1 ^= x0; }
  RR(13) RR(15) RR(26) RR(6)
  x0 += k1; x1 += k2 + 1u;
  RR(17) RR(29) RR(16) RR(24)
  x0 += k2; x1 += k0 + 2u;
  RR(13) RR(15) RR(26) RR(6)
  x0 += k0; x1 += k1 + 3u;
  RR(17) RR(29) RR(16) RR(24)
  x0 += k1; x1 += k2 + 4u;
  RR(13) RR(15) RR(26) RR(6)
  x0 += k2; x1 += k0 + 5u;
#undef RR
  o0 = x0; o1 = x1;
}

// Hot-loop threefry: counter (0, i), XOR-fold. Injection+round fused so the
// backend can emit v_add3_u32; (k0+k1) and (kX+c) are uniform -> SALU.
// All regroupings are mod-2^32 adds => bit-exact vs tf2x32.
__device__ __forceinline__ uint32_t tf_bits(uint32_t k0, uint32_t k1,
                                            uint32_t k2, uint32_t k01,
                                            uint32_t i) {
#define RN(r) { x0 += x1; x1 = rotl32(x1, r); x1 ^= x0; }
#define RF(kA, kBc, r) { x1 += (kBc); x0 = x0 + (kA) + x1; \
                         x1 = rotl32(x1, r); x1 ^= x0; }
  uint32_t x1 = i + k1;        // injected x1
  uint32_t x0 = i + k01;       // == k0 + x1, k01 = k0+k1 on SALU
  x1 = rotl32(x1, 13); x1 ^= x0;
  RN(15) RN(26) RN(6)
  RF(k1, k2 + 1u, 17) RN(29) RN(16) RN(24)
  RF(k2, k0 + 2u, 13) RN(15) RN(26) RN(6)
  RF(k0, k1 + 3u, 17) RN(29) RN(16) RN(24)
  RF(k1, k2 + 4u, 13) RN(15) RN(26) RN(6)
  return (x0 + k2) ^ (x1 + (k0 + 5u));
#undef RN
#undef RF
}

__device__ __forceinline__ float clamp01(float v) {
  return __builtin_amdgcn_fmed3f(v, 0.0f, 1.0f);  // == min(1,max(0,v)) finite
}

// noise = 0.1*sqrt2 * erfinv(u(b)), c folded into the polynomial coefficients.
__device__ __forceinline__ float noise_from_bits(uint32_t b) {
#pragma clang fp contract(off)
  // u in (-1,1): RN((b>>9)*2^-22 - 0.99999994) — bit-identical to the
  // bit-trick (exact cvt, single fma rounding; fmax(lo,.) provably no-op).
  float mf = (float)(b >> 9);              // v_cvt_f32_u32, exact (< 2^24)
  float x  = fmaf(mf, 0x1p-22f, -0.99999994f);
  float t = x * x;
  float u = 1.0f - t;      // two roundings, ref-identical; do NOT fma
  float L = __log2f(u);    // raw v_log_f32; u >= 3.6e-7, normal
  // s = w - 2.5 where w = -ln(u): fused, <=1 ulp vs (mul, neg-sub)
  float s = fmaf(L, -0x1.62e43p-1f, -2.5f);
  float p;
  if (__builtin_expect(!(s < 4.0f), 0)) {  // w >= 6.5, P ~ 0.075%/draw
    float s3 = sqrtf(s + 2.5f) - 3.0f;     // sqrt(w) - 3 (+-2ulp arg, benign)
    p = KC * -0.00367342844f;
    p = fmaf(p, s3, KC * 0.00573950773f);
    p = fmaf(p, s3, KC * -0.0076224613f);
    p = fmaf(p, s3, KC * 0.00943887047f);
    p = fmaf(p, s3, KC * 1.00167406f);
    p = fmaf(p, s3, KC * 2.83297682f);
  } else {
    p = KC * -4.39150654e-06f;
    p = fmaf(p, s, KC * 0.00021858087f);
    p = fmaf(p, s, KC * -0.00125372503f);
    p = fmaf(p, s, KC * -0.00417768164f);
    p = fmaf(p, s, KC * 0.246640727f);
    p = fmaf(p, s, KC * 1.50140941f);
  }
  return x * p;  // noise = x * (c*poly)
}

__global__ __launch_bounds__(256) void diffusion_kernel(
    const float* __restrict__ x, float* __restrict__ out) {
  // Step keys (partitionable split): key_t = threefry((0,1), (0,t)).
  // +1 pad slot so the t+1 prefetch never reads OOB.
  __shared__ alignas(16) uint2 skeys[TS + 1];
  const int tid = threadIdx.x;
  for (int j = tid; j < TS + 1; j += 256) {
    uint32_t o0, o1;
    tf2x32(0u, 1u, 0u, (uint32_t)(j < TS ? j : 0), o0, o1);
    skeys[j] = make_uint2(o0, o1);
  }
  __syncthreads();

  const uint32_t i = blockIdx.x * 256u + (uint32_t)tid;  // exact grid
  const uint32_t base = i * EPT;

  float4 xv = ((const float4*)x)[i];
  float v[EPT] = {xv.x, xv.y, xv.z, xv.w};

  uint2 kcur = skeys[0];
  for (int t = 0; t < TS; ++t) {
    const uint32_t k0 = (uint32_t)__builtin_amdgcn_readfirstlane((int)kcur.x);
    const uint32_t k1 = (uint32_t)__builtin_amdgcn_readfirstlane((int)kcur.y);
    kcur = skeys[t + 1];  // prefetch next key; waitcnt lands far from use
    const uint32_t k2  = k0 ^ k1 ^ 0x1BD11BDAu;  // uniform -> SALU
    const uint32_t k01 = k0 + k1;                // uniform -> SALU
    uint32_t b[EPT];
#pragma unroll
    for (uint32_t e = 0; e < EPT; ++e) b[e] = tf_bits(k0, k1, k2, k01, base + e);
#pragma unroll
    for (uint32_t e = 0; e < EPT; ++e) {
      v[e] = clamp01(v[e] + noise_from_bits(b[e]));
    }
  }

  // rev_key = fold_in(key(2), 999) = threefry((0,2),(0,999)) — constant-folded.
  uint32_t rk0, rk1;
  tf2x32(0u, 2u, 0u, 999u, rk0, rk1);
  const uint32_t rk2  = rk0 ^ rk1 ^ 0x1BD11BDAu;
  const uint32_t rk01 = rk0 + rk1;
  float4 ov;
  float* op = &ov.x;
#pragma unroll
  for (uint32_t e = 0; e < EPT; ++e) {
    float r = noise_from_bits(tf_bits(rk0, rk1, rk2, rk01, base + e));
    op[e] = clamp01(v[e] - r);
  }
  ((float4*)out)[i] = ov;
}

extern "C" void kernel_launch(void* const* d_in, const int* in_sizes, int n_in,
                              void* d_out, int out_size, void* d_ws, size_t ws_size,
                              hipStream_t stream) {
  (void)in_sizes; (void)n_in; (void)d_ws; (void)ws_size; (void)out_size;
  const float* x = (const float*)d_in[0];
  float* out = (float*)d_out;
  dim3 block(256);
  dim3 grid(NTHREADS / 256);  // 24576 blocks
  hipLaunchKernelGGL(diffusion_kernel, grid, block, 0, stream, x, out);
}